// Round 13
// baseline (442.898 us; speedup 1.0000x reference)
//
#include <hip/hip_runtime.h>
#include <hip/hip_bf16.h>
#include <math.h>

typedef __bf16 bf16;
typedef __bf16 bf16x8 __attribute__((ext_vector_type(8)));
typedef float f32x4 __attribute__((ext_vector_type(4)));

#define EPS 1e-5f

__device__ __forceinline__ int swz16(int row, int byteoff) {
  return byteoff ^ ((row & 7) << 4);
}

__device__ __forceinline__ void st_lds_bf16x2(char* lds, int off, float a, float b) {
  union { bf16 h[2]; unsigned u; } pk;
  pk.h[0] = (bf16)a; pk.h[1] = (bf16)b;
  *(unsigned*)(lds + off) = pk.u;
}

// async global->LDS, 16B per lane; LDS dest = wave-uniform base + lane*16
__device__ __forceinline__ void gl_lds16(const bf16* g, char* l) {
  __builtin_amdgcn_global_load_lds(
      (const __attribute__((address_space(1))) unsigned int*)(const void*)g,
      (__attribute__((address_space(3))) unsigned int*)l, 16, 0, 0);
}

// raw barrier: NO implicit vmcnt(0) drain (unlike __syncthreads)
__device__ __forceinline__ void bar_raw() {
  asm volatile("" ::: "memory");
  __builtin_amdgcn_s_barrier();
  asm volatile("" ::: "memory");
}

// tanh-form gelu via hw exp: max |err| vs exact ~1e-3, ~9 VALU ops (vs erff ~25)
__device__ __forceinline__ float gelu_fast(float x) {
  const float u2 = 1.5957691216f * (x + 0.044715f * x * x * x);  // 2*0.79788456*(x+..)
  const float e = __expf(u2);
  const float t = 1.f - 2.f / (e + 1.f);  // tanh(u)
  return 0.5f * x * (1.f + t);
}

// ---------------- prep: weights -> bf16 [N][K], rel_bias -> [6][64][64] ----------------
__global__ __launch_bounds__(256) void k_prep(
    const float* __restrict__ qkv_w, const float* __restrict__ proj_w,
    const float* __restrict__ mlp_w1, const float* __restrict__ mlp_w2,
    const float* __restrict__ rel_bias,
    bf16* __restrict__ w_qkv_t, bf16* __restrict__ w_proj_t,
    bf16* __restrict__ w_mlp1_t, bf16* __restrict__ w_mlp2_t,
    float* __restrict__ bias_tab) {
  int idx = blockIdx.x * 256 + threadIdx.x;
  if (idx < 110592) { int n = idx / 192, k = idx % 192; w_qkv_t[idx] = (bf16)qkv_w[k * 576 + n]; return; }
  idx -= 110592;
  if (idx < 36864) { int n = idx / 192, k = idx % 192; w_proj_t[idx] = (bf16)proj_w[k * 192 + n]; return; }
  idx -= 36864;
  if (idx < 147456) { int n = idx / 192, k = idx % 192; w_mlp1_t[idx] = (bf16)mlp_w1[k * 768 + n]; return; }
  idx -= 147456;
  if (idx < 147456) { int n = idx / 768, k = idx % 768; w_mlp2_t[idx] = (bf16)mlp_w2[k * 192 + n]; return; }
  idx -= 147456;
  {
    int h = idx >> 12, n = (idx >> 6) & 63, m = idx & 63;
    int i1 = n >> 3, j1 = n & 7, i2 = m >> 3, j2 = m & 7;
    int ridx = (i1 - i2 + 7) * 15 + (j1 - j2 + 7);
    bias_tab[idx] = rel_bias[ridx * 6 + h];
  }
}

// ---------------- K1a: LN1 + shift + window-partition -> xn (bf16, window-ordered) ----------------
__global__ __launch_bounds__(512) void k1a_ln(
    const float* __restrict__ x, const float* __restrict__ n1w, const float* __restrict__ n1b,
    bf16* __restrict__ xn) {
  const int win = blockIdx.x;
  const int bb = win >> 8, wi = (win >> 4) & 15, wj = win & 15;
  const int tid = threadIdx.x;
  const int t = tid >> 3, q = tid & 7;  // 8 threads per row
  const int i = t >> 3, j = t & 7;
  const int oh = (wi * 8 + i + 4) & 127, ow = (wj * 8 + j + 4) & 127;
  const float* xr = x + (((size_t)bb * 128 + oh) * 128 + ow) * 192 + q * 24;
  float v[24];
  float s = 0.f, ss = 0.f;
#pragma unroll
  for (int u = 0; u < 6; ++u) {
    float4 f = ((const float4*)xr)[u];
    v[4 * u] = f.x; v[4 * u + 1] = f.y; v[4 * u + 2] = f.z; v[4 * u + 3] = f.w;
    s += (f.x + f.y) + (f.z + f.w);
    ss += (f.x * f.x + f.y * f.y) + (f.z * f.z + f.w * f.w);
  }
  s += __shfl_xor(s, 1); s += __shfl_xor(s, 2); s += __shfl_xor(s, 4);
  ss += __shfl_xor(ss, 1); ss += __shfl_xor(ss, 2); ss += __shfl_xor(ss, 4);
  const float mean = s * (1.f / 192.f);
  const float rstd = rsqrtf(ss * (1.f / 192.f) - mean * mean + EPS);
  union { bf16 h[24]; uint4 u4[3]; } pk;
#pragma unroll
  for (int u = 0; u < 24; ++u) {
    const int c = q * 24 + u;
    pk.h[u] = (bf16)((v[u] - mean) * rstd * n1w[c] + n1b[c]);
  }
  uint4* dst = (uint4*)(xn + ((size_t)win * 64 + t) * 192 + q * 24);
#pragma unroll
  for (int u = 0; u < 3; ++u) dst[u] = pk.u4[u];
}

// ---------------- K1b: QKV GEMM (counted-vmcnt + raw-barrier pipeline) ----------------
// grid (1024 row-tiles, 3 col-blocks). tile 128 rows x 192 cols, K=192 (3 x BK=64).
__global__ __launch_bounds__(512, 4) void k1b_qkv(
    const bf16* __restrict__ xn, const bf16* __restrict__ wqkv, const float* __restrict__ qkvb,
    bf16* __restrict__ qbuf, bf16* __restrict__ kbuf, bf16* __restrict__ vtbuf) {
  __shared__ alignas(16) char ldsA[2][16384];
  __shared__ alignas(16) char ldsB[2][24576];
  const int blk = blockIdx.x, cb = blockIdx.y;
  const int tid = threadIdx.x;
  const int wid = tid >> 6, lane = tid & 63, lr = lane & 15, lg = lane >> 4;
  const int wr = wid >> 1, wc = wid & 1;
  const bf16* hA = xn + (size_t)blk * 128 * 192;
  const bf16* wB = wqkv + (size_t)cb * 192 * 192;

  auto stage = [&](int buf, int kt) {
    const int ko = kt * 64;
#pragma unroll
    for (int i = 0; i < 2; ++i) {
      const int slot = i * 512 + wid * 64 + lane;
      const int r = slot >> 3, c = slot & 7;
      gl_lds16(hA + (size_t)r * 192 + ko + ((c ^ (r & 7)) << 3),
               ldsA[buf] + (i * 512 + wid * 64) * 16);
    }
#pragma unroll
    for (int i = 0; i < 3; ++i) {
      const int slot = i * 512 + wid * 64 + lane;
      const int r = slot >> 3, c = slot & 7;
      gl_lds16(wB + (size_t)r * 192 + ko + ((c ^ (r & 7)) << 3),
               ldsB[buf] + (i * 512 + wid * 64) * 16);
    }
  };

  f32x4 acc[2][6] = {};
  stage(0, 0);
  int cur = 0;
  for (int kt = 0; kt < 3; ++kt) {
    if (kt < 2) {
      stage(cur ^ 1, kt + 1);
      asm volatile("s_waitcnt vmcnt(5)" ::: "memory");
    } else {
      asm volatile("s_waitcnt vmcnt(0)" ::: "memory");
    }
    bar_raw();
#pragma unroll
    for (int ks = 0; ks < 2; ++ks) {
      bf16x8 af[2];
#pragma unroll
      for (int rf = 0; rf < 2; ++rf) {
        const int row = wr * 32 + rf * 16 + lr;
        af[rf] = *(const bf16x8*)(ldsA[cur] + row * 128 + (((ks * 4 + lg) ^ (row & 7)) << 4));
      }
#pragma unroll
      for (int cf = 0; cf < 6; ++cf) {
        const int col = wc * 96 + cf * 16 + lr;
        const bf16x8 bfr = *(const bf16x8*)(ldsB[cur] + col * 128 + (((ks * 4 + lg) ^ (col & 7)) << 4));
#pragma unroll
        for (int rf = 0; rf < 2; ++rf)
          acc[rf][cf] = __builtin_amdgcn_mfma_f32_16x16x32_bf16(af[rf], bfr, acc[rf][cf], 0, 0, 0);
      }
    }
    bar_raw();
    cur ^= 1;
  }
  const float scale = 0.1767766952966369f;  // 1/sqrt(32)
  if (cb < 2) {
    bf16* dst = (cb == 0) ? qbuf : kbuf;
    const float sc = (cb == 0) ? scale : 1.f;
#pragma unroll
    for (int rf = 0; rf < 2; ++rf) {
#pragma unroll
      for (int jj = 0; jj < 4; ++jj) {
        const size_t grow = (size_t)blk * 128 + wr * 32 + rf * 16 + lg * 4 + jj;
#pragma unroll
        for (int cf = 0; cf < 6; ++cf) {
          const int col = wc * 96 + cf * 16 + lr;
          dst[grow * 192 + col] = (bf16)((acc[rf][cf][jj] + qkvb[cb * 192 + col]) * sc);
        }
      }
    }
  } else {
    // stage v tile [128 rows][192 d] in ldsB (48KB) swizzled, then transposed copy-out
    char* vlds = (char*)ldsB;
#pragma unroll
    for (int cf = 0; cf < 6; ++cf) {
      const int col = wc * 96 + cf * 16 + lr;
      const float bias = qkvb[384 + col];
#pragma unroll
      for (int rf = 0; rf < 2; ++rf)
#pragma unroll
        for (int jj = 0; jj < 4; ++jj) {
          const int row = wr * 32 + rf * 16 + lg * 4 + jj;
          *(bf16*)(vlds + swz16(row, row * 384 + col * 2)) = (bf16)(acc[rf][cf][jj] + bias);
        }
    }
    __syncthreads();
#pragma unroll
    for (int it = 0; it < 12; ++it) {
      const int idx = it * 512 + tid;
      const int w = idx / 3072, rem = idx % 3072;
      const int d = rem >> 4, tg = rem & 15;
      union { ushort u[4]; uint2 v; } pk;
#pragma unroll
      for (int j = 0; j < 4; ++j) {
        const int row = w * 64 + tg * 4 + j;
        pk.u[j] = *(const ushort*)(vlds + swz16(row, row * 384 + d * 2));
      }
      const int head = d >> 5, dd = d & 31;
      const int win = blk * 2 + w;
      *(uint2*)(vtbuf + ((size_t)win * 6 + head) * 2048 + dd * 64 + tg * 4) = pk.v;
    }
  }
}

// ---------------- K2: windowed attention, 6 waves (one per head) per window ----------------
__global__ __launch_bounds__(384) void k2_attn(
    const bf16* __restrict__ qbuf, const bf16* __restrict__ kbuf,
    const bf16* __restrict__ vtbuf, const float* __restrict__ btab_all,
    bf16* __restrict__ obuf) {
  __shared__ alignas(16) char p_lds_all[6 * 64 * 128];
  const int win = blockIdx.x;
  const int head = threadIdx.x >> 6;
  char* p_lds = p_lds_all + head * 64 * 128;
  const int lane = threadIdx.x & 63, lr = lane & 15, lg = lane >> 4;
  const bf16* qb = qbuf + (size_t)win * 12288 + head * 32;
  const bf16* kb = kbuf + (size_t)win * 12288 + head * 32;
  const bf16* vb = vtbuf + ((size_t)win * 6 + head) * 2048;
  f32x4 sacc[4][4] = {};
  bf16x8 bk[4];
#pragma unroll
  for (int cf = 0; cf < 4; ++cf)
    bk[cf] = *(const bf16x8*)(kb + (size_t)(cf * 16 + lr) * 192 + lg * 8);
#pragma unroll
  for (int rf = 0; rf < 4; ++rf) {
    const bf16x8 aq = *(const bf16x8*)(qb + (size_t)(rf * 16 + lr) * 192 + lg * 8);
#pragma unroll
    for (int cf = 0; cf < 4; ++cf)
      sacc[rf][cf] = __builtin_amdgcn_mfma_f32_16x16x32_bf16(aq, bk[cf], sacc[rf][cf], 0, 0, 0);
  }
  const int wi = (win >> 4) & 15, wj = win & 15;
  const bool eh = (wi == 15), ew = (wj == 15);
  const float* btab = btab_all + head * 4096;
#pragma unroll
  for (int rf = 0; rf < 4; ++rf) {
#pragma unroll
    for (int jj = 0; jj < 4; ++jj) {
      const int n = rf * 16 + lg * 4 + jj;
      const int i1 = n >> 3, j1 = n & 7;
      float vals[4];
#pragma unroll
      for (int cf = 0; cf < 4; ++cf) {
        const int m = cf * 16 + lr;
        const int i2 = m >> 3, j2 = m & 7;
        float sv = sacc[rf][cf][jj] + btab[n * 64 + m];
        const bool msk = (eh && ((i1 >= 4) != (i2 >= 4))) || (ew && ((j1 >= 4) != (j2 >= 4)));
        if (msk) sv -= 100.f;
        vals[cf] = sv;
      }
      float mx = fmaxf(fmaxf(vals[0], vals[1]), fmaxf(vals[2], vals[3]));
      mx = fmaxf(mx, __shfl_xor(mx, 1));
      mx = fmaxf(mx, __shfl_xor(mx, 2));
      mx = fmaxf(mx, __shfl_xor(mx, 4));
      mx = fmaxf(mx, __shfl_xor(mx, 8));
      float sum = 0.f;
#pragma unroll
      for (int cf = 0; cf < 4; ++cf) { vals[cf] = __expf(vals[cf] - mx); sum += vals[cf]; }
      sum += __shfl_xor(sum, 1); sum += __shfl_xor(sum, 2);
      sum += __shfl_xor(sum, 4); sum += __shfl_xor(sum, 8);
      const float inv = 1.f / sum;
#pragma unroll
      for (int cf = 0; cf < 4; ++cf) {
        const int m = cf * 16 + lr;
        *(bf16*)(p_lds + swz16(n, n * 128 + m * 2)) = (bf16)(vals[cf] * inv);
      }
    }
  }
  __syncthreads();
  f32x4 oacc[4][2] = {};
#pragma unroll
  for (int ks = 0; ks < 2; ++ks) {
    bf16x8 pf[4];
#pragma unroll
    for (int rf = 0; rf < 4; ++rf) {
      const int row = rf * 16 + lr;
      pf[rf] = *(const bf16x8*)(p_lds + swz16(row, row * 128 + (ks * 32 + lg * 8) * 2));
    }
#pragma unroll
    for (int cf = 0; cf < 2; ++cf) {
      const bf16x8 vf = *(const bf16x8*)(vb + (cf * 16 + lr) * 64 + ks * 32 + lg * 8);
#pragma unroll
      for (int rf = 0; rf < 4; ++rf)
        oacc[rf][cf] = __builtin_amdgcn_mfma_f32_16x16x32_bf16(pf[rf], vf, oacc[rf][cf], 0, 0, 0);
    }
  }
  bf16* ob = obuf + (size_t)win * 64 * 192 + head * 32;
#pragma unroll
  for (int rf = 0; rf < 4; ++rf)
#pragma unroll
    for (int cf = 0; cf < 2; ++cf)
#pragma unroll
      for (int jj = 0; jj < 4; ++jj) {
        const int tok = rf * 16 + lg * 4 + jj;
        const int d = cf * 16 + lr;
        ob[(size_t)tok * 192 + d] = (bf16)oacc[rf][cf][jj];
      }
}

// ---------------- K3: proj GEMM (counted-vmcnt + raw-barrier) + window-reverse + residual -> x2 ----------------
__global__ __launch_bounds__(512, 4) void k3_proj(
    const bf16* __restrict__ obuf, const bf16* __restrict__ wproj,
    const float* __restrict__ projb, const float* __restrict__ x,
    bf16* __restrict__ x2) {
  __shared__ alignas(16) char ldsA[2][16384];
  __shared__ alignas(16) char ldsB[2][24576];
  const int blk = blockIdx.x;
  const int tid = threadIdx.x;
  const int wid = tid >> 6, lane = tid & 63, lr = lane & 15, lg = lane >> 4;
  const int wr = wid >> 1, wc = wid & 1;
  const bf16* hA = obuf + (size_t)blk * 128 * 192;

  auto stage = [&](int buf, int kt) {
    const int ko = kt * 64;
#pragma unroll
    for (int i = 0; i < 2; ++i) {
      const int slot = i * 512 + wid * 64 + lane;
      const int r = slot >> 3, c = slot & 7;
      gl_lds16(hA + (size_t)r * 192 + ko + ((c ^ (r & 7)) << 3),
               ldsA[buf] + (i * 512 + wid * 64) * 16);
    }
#pragma unroll
    for (int i = 0; i < 3; ++i) {
      const int slot = i * 512 + wid * 64 + lane;
      const int r = slot >> 3, c = slot & 7;
      gl_lds16(wproj + (size_t)r * 192 + ko + ((c ^ (r & 7)) << 3),
               ldsB[buf] + (i * 512 + wid * 64) * 16);
    }
  };

  f32x4 acc[2][6] = {};
  stage(0, 0);
  int cur = 0;
  for (int kt = 0; kt < 3; ++kt) {
    if (kt < 2) {
      stage(cur ^ 1, kt + 1);
      asm volatile("s_waitcnt vmcnt(5)" ::: "memory");
    } else {
      asm volatile("s_waitcnt vmcnt(0)" ::: "memory");
    }
    bar_raw();
#pragma unroll
    for (int ks = 0; ks < 2; ++ks) {
      bf16x8 af[2];
#pragma unroll
      for (int rf = 0; rf < 2; ++rf) {
        const int row = wr * 32 + rf * 16 + lr;
        af[rf] = *(const bf16x8*)(ldsA[cur] + row * 128 + (((ks * 4 + lg) ^ (row & 7)) << 4));
      }
#pragma unroll
      for (int cf = 0; cf < 6; ++cf) {
        const int col = wc * 96 + cf * 16 + lr;
        const bf16x8 bfr = *(const bf16x8*)(ldsB[cur] + col * 128 + (((ks * 4 + lg) ^ (col & 7)) << 4));
#pragma unroll
        for (int rf = 0; rf < 2; ++rf)
          acc[rf][cf] = __builtin_amdgcn_mfma_f32_16x16x32_bf16(af[rf], bfr, acc[rf][cf], 0, 0, 0);
      }
    }
    bar_raw();
    cur ^= 1;
  }
#pragma unroll
  for (int rf = 0; rf < 2; ++rf) {
#pragma unroll
    for (int jj = 0; jj < 4; ++jj) {
      const int grow = blk * 128 + wr * 32 + rf * 16 + lg * 4 + jj;
      const int win = grow >> 6, t = grow & 63;
      const int bb = win >> 8, wi = (win >> 4) & 15, wj = win & 15;
      const int oh = (wi * 8 + (t >> 3) + 4) & 127, ow = (wj * 8 + (t & 7) + 4) & 127;
      const size_t orow = (((size_t)bb * 128 + oh) * 128 + ow) * 192;
#pragma unroll
      for (int cf = 0; cf < 6; ++cf) {
        const int col = wc * 96 + cf * 16 + lr;
        x2[orow + col] = (bf16)(x[orow + col] + acc[rf][cf][jj] + projb[col]);
      }
    }
  }
}

// ---------------- K4ln: LN2 streaming pass, x2(bf16) -> xln(bf16) ----------------
__global__ __launch_bounds__(512) void k4ln(
    const bf16* __restrict__ x2, const float* __restrict__ n2w, const float* __restrict__ n2b,
    bf16* __restrict__ xln) {
  const int tid = threadIdx.x;
  const int t = tid >> 3, q = tid & 7;
  const size_t row = (size_t)blockIdx.x * 64 + t;
  const bf16* xr = x2 + row * 192 + q * 24;
  float v[24];
  float s = 0.f, ss = 0.f;
#pragma unroll
  for (int u = 0; u < 3; ++u) {
    const bf16x8 f = ((const bf16x8*)xr)[u];
#pragma unroll
    for (int e = 0; e < 8; ++e) {
      const float fv = (float)f[e];
      v[8 * u + e] = fv;
      s += fv; ss += fv * fv;
    }
  }
  s += __shfl_xor(s, 1); s += __shfl_xor(s, 2); s += __shfl_xor(s, 4);
  ss += __shfl_xor(ss, 1); ss += __shfl_xor(ss, 2); ss += __shfl_xor(ss, 4);
  const float mean = s * (1.f / 192.f);
  const float rstd = rsqrtf(ss * (1.f / 192.f) - mean * mean + EPS);
  union { bf16 h[24]; uint4 u4[3]; } pk;
#pragma unroll
  for (int u = 0; u < 24; ++u) {
    const int c = q * 24 + u;
    pk.h[u] = (bf16)((v[u] - mean) * rstd * n2w[c] + n2b[c]);
  }
  uint4* dst = (uint4*)(xln + row * 192 + q * 24);
#pragma unroll
  for (int u = 0; u < 3; ++u) dst[u] = pk.u4[u];
}

// ---------------- K4a: MLP GEMM1 (counted-vmcnt + raw-barrier) + fast gelu -> h1 ----------------
// grid (1024 row-tiles, 4 col-blocks of 192). tile 128x192, K=192.
__global__ __launch_bounds__(512, 4) void k4a_gemm(
    const bf16* __restrict__ xln, const bf16* __restrict__ w1t, const float* __restrict__ b1,
    bf16* __restrict__ h1) {
  __shared__ alignas(16) char ldsA[2][16384];
  __shared__ alignas(16) char ldsB[2][24576];
  const int blk = blockIdx.x, cb = blockIdx.y;
  const int tid = threadIdx.x;
  const int wid = tid >> 6, lane = tid & 63, lr = lane & 15, lg = lane >> 4;
  const int wr = wid >> 1, wc = wid & 1;
  const bf16* hA = xln + (size_t)blk * 128 * 192;
  const bf16* wB = w1t + (size_t)cb * 192 * 192;

  auto stage = [&](int buf, int kt) {
    const int ko = kt * 64;
#pragma unroll
    for (int i = 0; i < 2; ++i) {
      const int slot = i * 512 + wid * 64 + lane;
      const int r = slot >> 3, c = slot & 7;
      gl_lds16(hA + (size_t)r * 192 + ko + ((c ^ (r & 7)) << 3),
               ldsA[buf] + (i * 512 + wid * 64) * 16);
    }
#pragma unroll
    for (int i = 0; i < 3; ++i) {
      const int slot = i * 512 + wid * 64 + lane;
      const int r = slot >> 3, c = slot & 7;
      gl_lds16(wB + (size_t)r * 192 + ko + ((c ^ (r & 7)) << 3),
               ldsB[buf] + (i * 512 + wid * 64) * 16);
    }
  };

  f32x4 acc[2][6] = {};
  stage(0, 0);
  int cur = 0;
  for (int kt = 0; kt < 3; ++kt) {
    if (kt < 2) {
      stage(cur ^ 1, kt + 1);
      asm volatile("s_waitcnt vmcnt(5)" ::: "memory");
    } else {
      asm volatile("s_waitcnt vmcnt(0)" ::: "memory");
    }
    bar_raw();
#pragma unroll
    for (int ks = 0; ks < 2; ++ks) {
      bf16x8 af[2];
#pragma unroll
      for (int rf = 0; rf < 2; ++rf) {
        const int row = wr * 32 + rf * 16 + lr;
        af[rf] = *(const bf16x8*)(ldsA[cur] + row * 128 + (((ks * 4 + lg) ^ (row & 7)) << 4));
      }
#pragma unroll
      for (int cf = 0; cf < 6; ++cf) {
        const int col = wc * 96 + cf * 16 + lr;
        const bf16x8 bfr = *(const bf16x8*)(ldsB[cur] + col * 128 + (((ks * 4 + lg) ^ (col & 7)) << 4));
#pragma unroll
        for (int rf = 0; rf < 2; ++rf)
          acc[rf][cf] = __builtin_amdgcn_mfma_f32_16x16x32_bf16(af[rf], bfr, acc[rf][cf], 0, 0, 0);
      }
    }
    bar_raw();
    cur ^= 1;
  }
#pragma unroll
  for (int rf = 0; rf < 2; ++rf) {
#pragma unroll
    for (int jj = 0; jj < 4; ++jj) {
      const size_t grow = (size_t)blk * 128 + wr * 32 + rf * 16 + lg * 4 + jj;
#pragma unroll
      for (int cf = 0; cf < 6; ++cf) {
        const int col = wc * 96 + cf * 16 + lr;
        const float vv = acc[rf][cf][jj] + b1[cb * 192 + col];
        h1[grow * 768 + cb * 192 + col] = (bf16)gelu_fast(vv);
      }
    }
  }
}

// ---------------- K4b: MLP GEMM2 v3 — A direct-to-registers, B triple-buffered LDS ----------------
__global__ __launch_bounds__(256, 2) void k4b_mlp2(
    const bf16* __restrict__ h1, const bf16* __restrict__ w2t,
    const float* __restrict__ b2, const bf16* __restrict__ x2,
    float* __restrict__ out) {
  __shared__ alignas(16) char ldsB[3][24576];
  const int blk = blockIdx.x;
  const int tid = threadIdx.x;
  const int wid = tid >> 6, lane = tid & 63, lr = lane & 15, lg = lane >> 4;
  const bf16* hA = h1 + ((size_t)blk * 128 + wid * 32) * 768;

  auto stageB = [&](int buf, int kt) {
    const int ko = kt * 64;
#pragma unroll
    for (int i = 0; i < 6; ++i) {
      const int slot = i * 256 + wid * 64 + lane;
      const int r = slot >> 3, c = slot & 7;
      gl_lds16(w2t + (size_t)r * 768 + ko + ((c ^ (r & 7)) << 3),
               ldsB[buf] + (i * 256 + wid * 64) * 16);
    }
  };

  f32x4 acc[2][12] = {};
  stageB(0, 0);
  int cur = 0, nxt = 1;
  for (int kt = 0; kt < 12; ++kt) {
    bf16x8 a0[2], a1[2];
#pragma unroll
    for (int rf = 0; rf < 2; ++rf) {
      const bf16* ar = hA + (size_t)(rf * 16 + lr) * 768 + kt * 64 + lg * 8;
      a0[rf] = *(const bf16x8*)(ar);
      a1[rf] = *(const bf16x8*)(ar + 32);
    }
    if (kt < 11) {
      stageB(nxt, kt + 1);
      asm volatile("s_waitcnt vmcnt(10)" ::: "memory");
    } else {
      asm volatile("s_waitcnt vmcnt(4)" ::: "memory");
    }
    bar_raw();
    const char* bcur = ldsB[cur];
#pragma unroll
    for (int ks = 0; ks < 2; ++ks) {
#pragma unroll
      for (int cf = 0; cf < 12; ++cf) {
        const int col = cf * 16 + lr;
        const bf16x8 bfr = *(const bf16x8*)(bcur + col * 128 + (((ks * 4 + lg) ^ (col & 7)) << 4));
        if (ks == 0) {
          acc[0][cf] = __builtin_amdgcn_mfma_f32_16x16x32_bf16(a0[0], bfr, acc[0][cf], 0, 0, 0);
          acc[1][cf] = __builtin_amdgcn_mfma_f32_16x16x32_bf16(a0[1], bfr, acc[1][cf], 0, 0, 0);
        } else {
          acc[0][cf] = __builtin_amdgcn_mfma_f32_16x16x32_bf16(a1[0], bfr, acc[0][cf], 0, 0, 0);
          acc[1][cf] = __builtin_amdgcn_mfma_f32_16x16x32_bf16(a1[1], bfr, acc[1][cf], 0, 0, 0);
        }
      }
    }
    cur = nxt; nxt = (nxt == 2) ? 0 : nxt + 1;
  }
#pragma unroll
  for (int rf = 0; rf < 2; ++rf) {
#pragma unroll
    for (int jj = 0; jj < 4; ++jj) {
      const size_t grow = (size_t)blk * 128 + wid * 32 + rf * 16 + lg * 4 + jj;
#pragma unroll
      for (int cf = 0; cf < 12; ++cf) {
        const int col = cf * 16 + lr;
        out[grow * 192 + col] = (float)x2[grow * 192 + col] + acc[rf][cf][jj] + b2[col];
      }
    }
  }
}

extern "C" void kernel_launch(void* const* d_in, const int* in_sizes, int n_in,
                              void* d_out, int out_size, void* d_ws, size_t ws_size,
                              hipStream_t stream) {
  (void)in_sizes; (void)n_in; (void)out_size; (void)ws_size;
  const float* x     = (const float*)d_in[0];
  const float* n1w   = (const float*)d_in[1];
  const float* n1b   = (const float*)d_in[2];
  const float* qkv_w = (const float*)d_in[3];
  const float* qkv_b = (const float*)d_in[4];
  const float* rel_b = (const float*)d_in[5];
  const float* proj_w= (const float*)d_in[6];
  const float* proj_b= (const float*)d_in[7];
  const float* n2w   = (const float*)d_in[8];
  const float* n2b   = (const float*)d_in[9];
  const float* w1    = (const float*)d_in[10];
  const float* b1    = (const float*)d_in[11];
  const float* w2    = (const float*)d_in[12];
  const float* b2    = (const float*)d_in[13];
  float* out = (float*)d_out;

  char* ws = (char*)d_ws;
  size_t off = 0;
  auto alloc = [&](size_t bytes) { char* p = ws + off; off += (bytes + 255) & ~(size_t)255; return p; };
  bf16* w_qkv_t  = (bf16*)alloc(576 * 192 * 2);
  bf16* w_proj_t = (bf16*)alloc(192 * 192 * 2);
  bf16* w_mlp1_t = (bf16*)alloc(768 * 192 * 2);
  bf16* w_mlp2_t = (bf16*)alloc(192 * 768 * 2);
  float* bias_tab = (float*)alloc(6 * 64 * 64 * 4);
  bf16* xn    = (bf16*)alloc((size_t)131072 * 192 * 2);
  bf16* qbuf  = (bf16*)alloc((size_t)131072 * 192 * 2);
  bf16* kbuf  = (bf16*)alloc((size_t)131072 * 192 * 2);
  bf16* vtbuf = (bf16*)alloc((size_t)2048 * 6 * 64 * 32 * 2);
  bf16* obuf  = (bf16*)alloc((size_t)131072 * 192 * 2);
  bf16* x2    = (bf16*)alloc((size_t)131072 * 192 * 2);
  bf16* h1  = xn;    // alias: xn/q/k/vt dead after k3 (201 MB)
  bf16* xln = obuf;  // alias: obuf dead after k3 (50 MB)

  k_prep<<<1824, 256, 0, stream>>>(qkv_w, proj_w, w1, w2, rel_b,
                                   w_qkv_t, w_proj_t, w_mlp1_t, w_mlp2_t, bias_tab);
  k1a_ln<<<2048, 512, 0, stream>>>(x, n1w, n1b, xn);
  k1b_qkv<<<dim3(1024, 3), 512, 0, stream>>>(xn, w_qkv_t, qkv_b, qbuf, kbuf, vtbuf);
  k2_attn<<<2048, 384, 0, stream>>>(qbuf, kbuf, vtbuf, bias_tab, obuf);
  k3_proj<<<1024, 512, 0, stream>>>(obuf, w_proj_t, proj_b, x, x2);
  k4ln<<<2048, 512, 0, stream>>>(x2, n2w, n2b, xln);
  k4a_gemm<<<dim3(1024, 4), 512, 0, stream>>>(xln, w_mlp1_t, b1, h1);
  k4b_mlp2<<<1024, 256, 0, stream>>>(h1, w_mlp2_t, b2, x2, out);
}

// Round 14
// 421.588 us; speedup vs baseline: 1.0505x; 1.0505x over previous
//
#include <hip/hip_runtime.h>
#include <hip/hip_bf16.h>
#include <math.h>

typedef __bf16 bf16;
typedef __bf16 bf16x8 __attribute__((ext_vector_type(8)));
typedef float f32x4 __attribute__((ext_vector_type(4)));

#define EPS 1e-5f

__device__ __forceinline__ int swz16(int row, int byteoff) {
  return byteoff ^ ((row & 7) << 4);
}

__device__ __forceinline__ void st_lds_bf16x2(char* lds, int off, float a, float b) {
  union { bf16 h[2]; unsigned u; } pk;
  pk.h[0] = (bf16)a; pk.h[1] = (bf16)b;
  *(unsigned*)(lds + off) = pk.u;
}

// async global->LDS, 16B per lane; LDS dest = wave-uniform base + lane*16
__device__ __forceinline__ void gl_lds16(const bf16* g, char* l) {
  __builtin_amdgcn_global_load_lds(
      (const __attribute__((address_space(1))) unsigned int*)(const void*)g,
      (__attribute__((address_space(3))) unsigned int*)l, 16, 0, 0);
}

// raw barrier: NO implicit vmcnt(0) drain (unlike __syncthreads)
__device__ __forceinline__ void bar_raw() {
  asm volatile("" ::: "memory");
  __builtin_amdgcn_s_barrier();
  asm volatile("" ::: "memory");
}

// tanh-gelu mapped 1:1 to HW ops: x*sigmoid(2u), 2u*log2e = x*(2.302135+0.102940x^2)
// v_mul, v_fma, v_mul, v_exp_f32, v_add, v_rcp_f32, v_fma  — no IEEE div, no libm.
__device__ __forceinline__ float gelu_fast(float x) {
  const float x2 = x * x;
  const float z = x * (2.302135f + 0.102940f * x2);
  const float e = __builtin_amdgcn_exp2f(z);           // v_exp_f32 (exp2)
  const float r = __builtin_amdgcn_rcpf(1.f + e);      // v_rcp_f32
  return x - x * r;  // x*(1 - 1/(1+e)) ; e->inf => x ; e->0 => 0
}

// ---------------- prep: weights -> bf16 [N][K], rel_bias -> [6][64][64] ----------------
__global__ __launch_bounds__(256) void k_prep(
    const float* __restrict__ qkv_w, const float* __restrict__ proj_w,
    const float* __restrict__ mlp_w1, const float* __restrict__ mlp_w2,
    const float* __restrict__ rel_bias,
    bf16* __restrict__ w_qkv_t, bf16* __restrict__ w_proj_t,
    bf16* __restrict__ w_mlp1_t, bf16* __restrict__ w_mlp2_t,
    float* __restrict__ bias_tab) {
  int idx = blockIdx.x * 256 + threadIdx.x;
  if (idx < 110592) { int n = idx / 192, k = idx % 192; w_qkv_t[idx] = (bf16)qkv_w[k * 576 + n]; return; }
  idx -= 110592;
  if (idx < 36864) { int n = idx / 192, k = idx % 192; w_proj_t[idx] = (bf16)proj_w[k * 192 + n]; return; }
  idx -= 36864;
  if (idx < 147456) { int n = idx / 192, k = idx % 192; w_mlp1_t[idx] = (bf16)mlp_w1[k * 768 + n]; return; }
  idx -= 147456;
  if (idx < 147456) { int n = idx / 768, k = idx % 768; w_mlp2_t[idx] = (bf16)mlp_w2[k * 192 + n]; return; }
  idx -= 147456;
  {
    int h = idx >> 12, n = (idx >> 6) & 63, m = idx & 63;
    int i1 = n >> 3, j1 = n & 7, i2 = m >> 3, j2 = m & 7;
    int ridx = (i1 - i2 + 7) * 15 + (j1 - j2 + 7);
    bias_tab[idx] = rel_bias[ridx * 6 + h];
  }
}

// ---------------- K1a: LN1 + shift + window-partition -> xn (bf16, window-ordered) ----------------
__global__ __launch_bounds__(512) void k1a_ln(
    const float* __restrict__ x, const float* __restrict__ n1w, const float* __restrict__ n1b,
    bf16* __restrict__ xn) {
  const int win = blockIdx.x;
  const int bb = win >> 8, wi = (win >> 4) & 15, wj = win & 15;
  const int tid = threadIdx.x;
  const int t = tid >> 3, q = tid & 7;  // 8 threads per row
  const int i = t >> 3, j = t & 7;
  const int oh = (wi * 8 + i + 4) & 127, ow = (wj * 8 + j + 4) & 127;
  const float* xr = x + (((size_t)bb * 128 + oh) * 128 + ow) * 192 + q * 24;
  float v[24];
  float s = 0.f, ss = 0.f;
#pragma unroll
  for (int u = 0; u < 6; ++u) {
    float4 f = ((const float4*)xr)[u];
    v[4 * u] = f.x; v[4 * u + 1] = f.y; v[4 * u + 2] = f.z; v[4 * u + 3] = f.w;
    s += (f.x + f.y) + (f.z + f.w);
    ss += (f.x * f.x + f.y * f.y) + (f.z * f.z + f.w * f.w);
  }
  s += __shfl_xor(s, 1); s += __shfl_xor(s, 2); s += __shfl_xor(s, 4);
  ss += __shfl_xor(ss, 1); ss += __shfl_xor(ss, 2); ss += __shfl_xor(ss, 4);
  const float mean = s * (1.f / 192.f);
  const float rstd = rsqrtf(ss * (1.f / 192.f) - mean * mean + EPS);
  union { bf16 h[24]; uint4 u4[3]; } pk;
#pragma unroll
  for (int u = 0; u < 24; ++u) {
    const int c = q * 24 + u;
    pk.h[u] = (bf16)((v[u] - mean) * rstd * n1w[c] + n1b[c]);
  }
  uint4* dst = (uint4*)(xn + ((size_t)win * 64 + t) * 192 + q * 24);
#pragma unroll
  for (int u = 0; u < 3; ++u) dst[u] = pk.u4[u];
}

// ---------------- K1b: QKV GEMM (counted-vmcnt + raw-barrier pipeline) ----------------
// grid (1024 row-tiles, 3 col-blocks). tile 128 rows x 192 cols, K=192 (3 x BK=64).
__global__ __launch_bounds__(512, 4) void k1b_qkv(
    const bf16* __restrict__ xn, const bf16* __restrict__ wqkv, const float* __restrict__ qkvb,
    bf16* __restrict__ qbuf, bf16* __restrict__ kbuf, bf16* __restrict__ vtbuf) {
  __shared__ alignas(16) char ldsA[2][16384];
  __shared__ alignas(16) char ldsB[2][24576];
  const int blk = blockIdx.x, cb = blockIdx.y;
  const int tid = threadIdx.x;
  const int wid = tid >> 6, lane = tid & 63, lr = lane & 15, lg = lane >> 4;
  const int wr = wid >> 1, wc = wid & 1;
  const bf16* hA = xn + (size_t)blk * 128 * 192;
  const bf16* wB = wqkv + (size_t)cb * 192 * 192;

  auto stage = [&](int buf, int kt) {
    const int ko = kt * 64;
#pragma unroll
    for (int i = 0; i < 2; ++i) {
      const int slot = i * 512 + wid * 64 + lane;
      const int r = slot >> 3, c = slot & 7;
      gl_lds16(hA + (size_t)r * 192 + ko + ((c ^ (r & 7)) << 3),
               ldsA[buf] + (i * 512 + wid * 64) * 16);
    }
#pragma unroll
    for (int i = 0; i < 3; ++i) {
      const int slot = i * 512 + wid * 64 + lane;
      const int r = slot >> 3, c = slot & 7;
      gl_lds16(wB + (size_t)r * 192 + ko + ((c ^ (r & 7)) << 3),
               ldsB[buf] + (i * 512 + wid * 64) * 16);
    }
  };

  f32x4 acc[2][6] = {};
  stage(0, 0);
  int cur = 0;
  for (int kt = 0; kt < 3; ++kt) {
    if (kt < 2) {
      stage(cur ^ 1, kt + 1);
      asm volatile("s_waitcnt vmcnt(5)" ::: "memory");
    } else {
      asm volatile("s_waitcnt vmcnt(0)" ::: "memory");
    }
    bar_raw();
#pragma unroll
    for (int ks = 0; ks < 2; ++ks) {
      bf16x8 af[2];
#pragma unroll
      for (int rf = 0; rf < 2; ++rf) {
        const int row = wr * 32 + rf * 16 + lr;
        af[rf] = *(const bf16x8*)(ldsA[cur] + row * 128 + (((ks * 4 + lg) ^ (row & 7)) << 4));
      }
#pragma unroll
      for (int cf = 0; cf < 6; ++cf) {
        const int col = wc * 96 + cf * 16 + lr;
        const bf16x8 bfr = *(const bf16x8*)(ldsB[cur] + col * 128 + (((ks * 4 + lg) ^ (col & 7)) << 4));
#pragma unroll
        for (int rf = 0; rf < 2; ++rf)
          acc[rf][cf] = __builtin_amdgcn_mfma_f32_16x16x32_bf16(af[rf], bfr, acc[rf][cf], 0, 0, 0);
      }
    }
    bar_raw();
    cur ^= 1;
  }
  const float scale = 0.1767766952966369f;  // 1/sqrt(32)
  if (cb < 2) {
    bf16* dst = (cb == 0) ? qbuf : kbuf;
    const float sc = (cb == 0) ? scale : 1.f;
#pragma unroll
    for (int rf = 0; rf < 2; ++rf) {
#pragma unroll
      for (int jj = 0; jj < 4; ++jj) {
        const size_t grow = (size_t)blk * 128 + wr * 32 + rf * 16 + lg * 4 + jj;
#pragma unroll
        for (int cf = 0; cf < 6; ++cf) {
          const int col = wc * 96 + cf * 16 + lr;
          dst[grow * 192 + col] = (bf16)((acc[rf][cf][jj] + qkvb[cb * 192 + col]) * sc);
        }
      }
    }
  } else {
    // stage v tile [128 rows][192 d] in ldsB (48KB) swizzled, then transposed copy-out
    char* vlds = (char*)ldsB;
#pragma unroll
    for (int cf = 0; cf < 6; ++cf) {
      const int col = wc * 96 + cf * 16 + lr;
      const float bias = qkvb[384 + col];
#pragma unroll
      for (int rf = 0; rf < 2; ++rf)
#pragma unroll
        for (int jj = 0; jj < 4; ++jj) {
          const int row = wr * 32 + rf * 16 + lg * 4 + jj;
          *(bf16*)(vlds + swz16(row, row * 384 + col * 2)) = (bf16)(acc[rf][cf][jj] + bias);
        }
    }
    __syncthreads();
#pragma unroll
    for (int it = 0; it < 12; ++it) {
      const int idx = it * 512 + tid;
      const int w = idx / 3072, rem = idx % 3072;
      const int d = rem >> 4, tg = rem & 15;
      union { ushort u[4]; uint2 v; } pk;
#pragma unroll
      for (int j = 0; j < 4; ++j) {
        const int row = w * 64 + tg * 4 + j;
        pk.u[j] = *(const ushort*)(vlds + swz16(row, row * 384 + d * 2));
      }
      const int head = d >> 5, dd = d & 31;
      const int win = blk * 2 + w;
      *(uint2*)(vtbuf + ((size_t)win * 6 + head) * 2048 + dd * 64 + tg * 4) = pk.v;
    }
  }
}

// ---------------- K2: windowed attention, 6 waves (one per head) per window ----------------
__global__ __launch_bounds__(384) void k2_attn(
    const bf16* __restrict__ qbuf, const bf16* __restrict__ kbuf,
    const bf16* __restrict__ vtbuf, const float* __restrict__ btab_all,
    bf16* __restrict__ obuf) {
  __shared__ alignas(16) char p_lds_all[6 * 64 * 128];
  const int win = blockIdx.x;
  const int head = threadIdx.x >> 6;
  char* p_lds = p_lds_all + head * 64 * 128;
  const int lane = threadIdx.x & 63, lr = lane & 15, lg = lane >> 4;
  const bf16* qb = qbuf + (size_t)win * 12288 + head * 32;
  const bf16* kb = kbuf + (size_t)win * 12288 + head * 32;
  const bf16* vb = vtbuf + ((size_t)win * 6 + head) * 2048;
  f32x4 sacc[4][4] = {};
  bf16x8 bk[4];
#pragma unroll
  for (int cf = 0; cf < 4; ++cf)
    bk[cf] = *(const bf16x8*)(kb + (size_t)(cf * 16 + lr) * 192 + lg * 8);
#pragma unroll
  for (int rf = 0; rf < 4; ++rf) {
    const bf16x8 aq = *(const bf16x8*)(qb + (size_t)(rf * 16 + lr) * 192 + lg * 8);
#pragma unroll
    for (int cf = 0; cf < 4; ++cf)
      sacc[rf][cf] = __builtin_amdgcn_mfma_f32_16x16x32_bf16(aq, bk[cf], sacc[rf][cf], 0, 0, 0);
  }
  const int wi = (win >> 4) & 15, wj = win & 15;
  const bool eh = (wi == 15), ew = (wj == 15);
  const float* btab = btab_all + head * 4096;
#pragma unroll
  for (int rf = 0; rf < 4; ++rf) {
#pragma unroll
    for (int jj = 0; jj < 4; ++jj) {
      const int n = rf * 16 + lg * 4 + jj;
      const int i1 = n >> 3, j1 = n & 7;
      float vals[4];
#pragma unroll
      for (int cf = 0; cf < 4; ++cf) {
        const int m = cf * 16 + lr;
        const int i2 = m >> 3, j2 = m & 7;
        float sv = sacc[rf][cf][jj] + btab[n * 64 + m];
        const bool msk = (eh && ((i1 >= 4) != (i2 >= 4))) || (ew && ((j1 >= 4) != (j2 >= 4)));
        if (msk) sv -= 100.f;
        vals[cf] = sv;
      }
      float mx = fmaxf(fmaxf(vals[0], vals[1]), fmaxf(vals[2], vals[3]));
      mx = fmaxf(mx, __shfl_xor(mx, 1));
      mx = fmaxf(mx, __shfl_xor(mx, 2));
      mx = fmaxf(mx, __shfl_xor(mx, 4));
      mx = fmaxf(mx, __shfl_xor(mx, 8));
      float sum = 0.f;
#pragma unroll
      for (int cf = 0; cf < 4; ++cf) { vals[cf] = __expf(vals[cf] - mx); sum += vals[cf]; }
      sum += __shfl_xor(sum, 1); sum += __shfl_xor(sum, 2);
      sum += __shfl_xor(sum, 4); sum += __shfl_xor(sum, 8);
      const float inv = 1.f / sum;
#pragma unroll
      for (int cf = 0; cf < 4; ++cf) {
        const int m = cf * 16 + lr;
        *(bf16*)(p_lds + swz16(n, n * 128 + m * 2)) = (bf16)(vals[cf] * inv);
      }
    }
  }
  __syncthreads();
  f32x4 oacc[4][2] = {};
#pragma unroll
  for (int ks = 0; ks < 2; ++ks) {
    bf16x8 pf[4];
#pragma unroll
    for (int rf = 0; rf < 4; ++rf) {
      const int row = rf * 16 + lr;
      pf[rf] = *(const bf16x8*)(p_lds + swz16(row, row * 128 + (ks * 32 + lg * 8) * 2));
    }
#pragma unroll
    for (int cf = 0; cf < 2; ++cf) {
      const bf16x8 vf = *(const bf16x8*)(vb + (cf * 16 + lr) * 64 + ks * 32 + lg * 8);
#pragma unroll
      for (int rf = 0; rf < 4; ++rf)
        oacc[rf][cf] = __builtin_amdgcn_mfma_f32_16x16x32_bf16(pf[rf], vf, oacc[rf][cf], 0, 0, 0);
    }
  }
  bf16* ob = obuf + (size_t)win * 64 * 192 + head * 32;
#pragma unroll
  for (int rf = 0; rf < 4; ++rf)
#pragma unroll
    for (int cf = 0; cf < 2; ++cf)
#pragma unroll
      for (int jj = 0; jj < 4; ++jj) {
        const int tok = rf * 16 + lg * 4 + jj;
        const int d = cf * 16 + lr;
        ob[(size_t)tok * 192 + d] = (bf16)oacc[rf][cf][jj];
      }
}

// ---------------- K3: proj GEMM (counted-vmcnt + raw-barrier) + window-reverse + residual -> x2 ----------------
__global__ __launch_bounds__(512, 4) void k3_proj(
    const bf16* __restrict__ obuf, const bf16* __restrict__ wproj,
    const float* __restrict__ projb, const float* __restrict__ x,
    bf16* __restrict__ x2) {
  __shared__ alignas(16) char ldsA[2][16384];
  __shared__ alignas(16) char ldsB[2][24576];
  const int blk = blockIdx.x;
  const int tid = threadIdx.x;
  const int wid = tid >> 6, lane = tid & 63, lr = lane & 15, lg = lane >> 4;
  const int wr = wid >> 1, wc = wid & 1;
  const bf16* hA = obuf + (size_t)blk * 128 * 192;

  auto stage = [&](int buf, int kt) {
    const int ko = kt * 64;
#pragma unroll
    for (int i = 0; i < 2; ++i) {
      const int slot = i * 512 + wid * 64 + lane;
      const int r = slot >> 3, c = slot & 7;
      gl_lds16(hA + (size_t)r * 192 + ko + ((c ^ (r & 7)) << 3),
               ldsA[buf] + (i * 512 + wid * 64) * 16);
    }
#pragma unroll
    for (int i = 0; i < 3; ++i) {
      const int slot = i * 512 + wid * 64 + lane;
      const int r = slot >> 3, c = slot & 7;
      gl_lds16(wproj + (size_t)r * 192 + ko + ((c ^ (r & 7)) << 3),
               ldsB[buf] + (i * 512 + wid * 64) * 16);
    }
  };

  f32x4 acc[2][6] = {};
  stage(0, 0);
  int cur = 0;
  for (int kt = 0; kt < 3; ++kt) {
    if (kt < 2) {
      stage(cur ^ 1, kt + 1);
      asm volatile("s_waitcnt vmcnt(5)" ::: "memory");
    } else {
      asm volatile("s_waitcnt vmcnt(0)" ::: "memory");
    }
    bar_raw();
#pragma unroll
    for (int ks = 0; ks < 2; ++ks) {
      bf16x8 af[2];
#pragma unroll
      for (int rf = 0; rf < 2; ++rf) {
        const int row = wr * 32 + rf * 16 + lr;
        af[rf] = *(const bf16x8*)(ldsA[cur] + row * 128 + (((ks * 4 + lg) ^ (row & 7)) << 4));
      }
#pragma unroll
      for (int cf = 0; cf < 6; ++cf) {
        const int col = wc * 96 + cf * 16 + lr;
        const bf16x8 bfr = *(const bf16x8*)(ldsB[cur] + col * 128 + (((ks * 4 + lg) ^ (col & 7)) << 4));
#pragma unroll
        for (int rf = 0; rf < 2; ++rf)
          acc[rf][cf] = __builtin_amdgcn_mfma_f32_16x16x32_bf16(af[rf], bfr, acc[rf][cf], 0, 0, 0);
      }
    }
    bar_raw();
    cur ^= 1;
  }
#pragma unroll
  for (int rf = 0; rf < 2; ++rf) {
#pragma unroll
    for (int jj = 0; jj < 4; ++jj) {
      const int grow = blk * 128 + wr * 32 + rf * 16 + lg * 4 + jj;
      const int win = grow >> 6, t = grow & 63;
      const int bb = win >> 8, wi = (win >> 4) & 15, wj = win & 15;
      const int oh = (wi * 8 + (t >> 3) + 4) & 127, ow = (wj * 8 + (t & 7) + 4) & 127;
      const size_t orow = (((size_t)bb * 128 + oh) * 128 + ow) * 192;
#pragma unroll
      for (int cf = 0; cf < 6; ++cf) {
        const int col = wc * 96 + cf * 16 + lr;
        x2[orow + col] = (bf16)(x[orow + col] + acc[rf][cf][jj] + projb[col]);
      }
    }
  }
}

// ---------------- K4ln: LN2 streaming pass, x2(bf16) -> xln(bf16) ----------------
__global__ __launch_bounds__(512) void k4ln(
    const bf16* __restrict__ x2, const float* __restrict__ n2w, const float* __restrict__ n2b,
    bf16* __restrict__ xln) {
  const int tid = threadIdx.x;
  const int t = tid >> 3, q = tid & 7;
  const size_t row = (size_t)blockIdx.x * 64 + t;
  const bf16* xr = x2 + row * 192 + q * 24;
  float v[24];
  float s = 0.f, ss = 0.f;
#pragma unroll
  for (int u = 0; u < 3; ++u) {
    const bf16x8 f = ((const bf16x8*)xr)[u];
#pragma unroll
    for (int e = 0; e < 8; ++e) {
      const float fv = (float)f[e];
      v[8 * u + e] = fv;
      s += fv; ss += fv * fv;
    }
  }
  s += __shfl_xor(s, 1); s += __shfl_xor(s, 2); s += __shfl_xor(s, 4);
  ss += __shfl_xor(ss, 1); ss += __shfl_xor(ss, 2); ss += __shfl_xor(ss, 4);
  const float mean = s * (1.f / 192.f);
  const float rstd = rsqrtf(ss * (1.f / 192.f) - mean * mean + EPS);
  union { bf16 h[24]; uint4 u4[3]; } pk;
#pragma unroll
  for (int u = 0; u < 24; ++u) {
    const int c = q * 24 + u;
    pk.h[u] = (bf16)((v[u] - mean) * rstd * n2w[c] + n2b[c]);
  }
  uint4* dst = (uint4*)(xln + row * 192 + q * 24);
#pragma unroll
  for (int u = 0; u < 3; ++u) dst[u] = pk.u4[u];
}

// ---------------- K4a: MLP GEMM1 (counted-vmcnt + raw-barrier) + fast gelu -> h1 ----------------
// grid (1024 row-tiles, 4 col-blocks of 192). tile 128x192, K=192.
__global__ __launch_bounds__(512, 4) void k4a_gemm(
    const bf16* __restrict__ xln, const bf16* __restrict__ w1t, const float* __restrict__ b1,
    bf16* __restrict__ h1) {
  __shared__ alignas(16) char ldsA[2][16384];
  __shared__ alignas(16) char ldsB[2][24576];
  const int blk = blockIdx.x, cb = blockIdx.y;
  const int tid = threadIdx.x;
  const int wid = tid >> 6, lane = tid & 63, lr = lane & 15, lg = lane >> 4;
  const int wr = wid >> 1, wc = wid & 1;
  const bf16* hA = xln + (size_t)blk * 128 * 192;
  const bf16* wB = w1t + (size_t)cb * 192 * 192;

  auto stage = [&](int buf, int kt) {
    const int ko = kt * 64;
#pragma unroll
    for (int i = 0; i < 2; ++i) {
      const int slot = i * 512 + wid * 64 + lane;
      const int r = slot >> 3, c = slot & 7;
      gl_lds16(hA + (size_t)r * 192 + ko + ((c ^ (r & 7)) << 3),
               ldsA[buf] + (i * 512 + wid * 64) * 16);
    }
#pragma unroll
    for (int i = 0; i < 3; ++i) {
      const int slot = i * 512 + wid * 64 + lane;
      const int r = slot >> 3, c = slot & 7;
      gl_lds16(wB + (size_t)r * 192 + ko + ((c ^ (r & 7)) << 3),
               ldsB[buf] + (i * 512 + wid * 64) * 16);
    }
  };

  f32x4 acc[2][6] = {};
  stage(0, 0);
  int cur = 0;
  for (int kt = 0; kt < 3; ++kt) {
    if (kt < 2) {
      stage(cur ^ 1, kt + 1);
      asm volatile("s_waitcnt vmcnt(5)" ::: "memory");
    } else {
      asm volatile("s_waitcnt vmcnt(0)" ::: "memory");
    }
    bar_raw();
#pragma unroll
    for (int ks = 0; ks < 2; ++ks) {
      bf16x8 af[2];
#pragma unroll
      for (int rf = 0; rf < 2; ++rf) {
        const int row = wr * 32 + rf * 16 + lr;
        af[rf] = *(const bf16x8*)(ldsA[cur] + row * 128 + (((ks * 4 + lg) ^ (row & 7)) << 4));
      }
#pragma unroll
      for (int cf = 0; cf < 6; ++cf) {
        const int col = wc * 96 + cf * 16 + lr;
        const bf16x8 bfr = *(const bf16x8*)(ldsB[cur] + col * 128 + (((ks * 4 + lg) ^ (col & 7)) << 4));
#pragma unroll
        for (int rf = 0; rf < 2; ++rf)
          acc[rf][cf] = __builtin_amdgcn_mfma_f32_16x16x32_bf16(af[rf], bfr, acc[rf][cf], 0, 0, 0);
      }
    }
    bar_raw();
    cur ^= 1;
  }
#pragma unroll
  for (int rf = 0; rf < 2; ++rf) {
#pragma unroll
    for (int jj = 0; jj < 4; ++jj) {
      const size_t grow = (size_t)blk * 128 + wr * 32 + rf * 16 + lg * 4 + jj;
#pragma unroll
      for (int cf = 0; cf < 6; ++cf) {
        const int col = wc * 96 + cf * 16 + lr;
        const float vv = acc[rf][cf][jj] + b1[cb * 192 + col];
        h1[grow * 768 + cb * 192 + col] = (bf16)gelu_fast(vv);
      }
    }
  }
}

// ---------------- K4b: MLP GEMM2 v3 — A direct-to-registers, B triple-buffered LDS ----------------
__global__ __launch_bounds__(256, 2) void k4b_mlp2(
    const bf16* __restrict__ h1, const bf16* __restrict__ w2t,
    const float* __restrict__ b2, const bf16* __restrict__ x2,
    float* __restrict__ out) {
  __shared__ alignas(16) char ldsB[3][24576];
  const int blk = blockIdx.x;
  const int tid = threadIdx.x;
  const int wid = tid >> 6, lane = tid & 63, lr = lane & 15, lg = lane >> 4;
  const bf16* hA = h1 + ((size_t)blk * 128 + wid * 32) * 768;

  auto stageB = [&](int buf, int kt) {
    const int ko = kt * 64;
#pragma unroll
    for (int i = 0; i < 6; ++i) {
      const int slot = i * 256 + wid * 64 + lane;
      const int r = slot >> 3, c = slot & 7;
      gl_lds16(w2t + (size_t)r * 768 + ko + ((c ^ (r & 7)) << 3),
               ldsB[buf] + (i * 256 + wid * 64) * 16);
    }
  };

  f32x4 acc[2][12] = {};
  stageB(0, 0);
  int cur = 0, nxt = 1;
  for (int kt = 0; kt < 12; ++kt) {
    bf16x8 a0[2], a1[2];
#pragma unroll
    for (int rf = 0; rf < 2; ++rf) {
      const bf16* ar = hA + (size_t)(rf * 16 + lr) * 768 + kt * 64 + lg * 8;
      a0[rf] = *(const bf16x8*)(ar);
      a1[rf] = *(const bf16x8*)(ar + 32);
    }
    if (kt < 11) {
      stageB(nxt, kt + 1);
      asm volatile("s_waitcnt vmcnt(10)" ::: "memory");
    } else {
      asm volatile("s_waitcnt vmcnt(4)" ::: "memory");
    }
    bar_raw();
    const char* bcur = ldsB[cur];
#pragma unroll
    for (int ks = 0; ks < 2; ++ks) {
#pragma unroll
      for (int cf = 0; cf < 12; ++cf) {
        const int col = cf * 16 + lr;
        const bf16x8 bfr = *(const bf16x8*)(bcur + col * 128 + (((ks * 4 + lg) ^ (col & 7)) << 4));
        if (ks == 0) {
          acc[0][cf] = __builtin_amdgcn_mfma_f32_16x16x32_bf16(a0[0], bfr, acc[0][cf], 0, 0, 0);
          acc[1][cf] = __builtin_amdgcn_mfma_f32_16x16x32_bf16(a0[1], bfr, acc[1][cf], 0, 0, 0);
        } else {
          acc[0][cf] = __builtin_amdgcn_mfma_f32_16x16x32_bf16(a1[0], bfr, acc[0][cf], 0, 0, 0);
          acc[1][cf] = __builtin_amdgcn_mfma_f32_16x16x32_bf16(a1[1], bfr, acc[1][cf], 0, 0, 0);
        }
      }
    }
    cur = nxt; nxt = (nxt == 2) ? 0 : nxt + 1;
  }
#pragma unroll
  for (int rf = 0; rf < 2; ++rf) {
#pragma unroll
    for (int jj = 0; jj < 4; ++jj) {
      const size_t grow = (size_t)blk * 128 + wid * 32 + rf * 16 + lg * 4 + jj;
#pragma unroll
      for (int cf = 0; cf < 12; ++cf) {
        const int col = cf * 16 + lr;
        out[grow * 192 + col] = (float)x2[grow * 192 + col] + acc[rf][cf][jj] + b2[col];
      }
    }
  }
}

extern "C" void kernel_launch(void* const* d_in, const int* in_sizes, int n_in,
                              void* d_out, int out_size, void* d_ws, size_t ws_size,
                              hipStream_t stream) {
  (void)in_sizes; (void)n_in; (void)out_size; (void)ws_size;
  const float* x     = (const float*)d_in[0];
  const float* n1w   = (const float*)d_in[1];
  const float* n1b   = (const float*)d_in[2];
  const float* qkv_w = (const float*)d_in[3];
  const float* qkv_b = (const float*)d_in[4];
  const float* rel_b = (const float*)d_in[5];
  const float* proj_w= (const float*)d_in[6];
  const float* proj_b= (const float*)d_in[7];
  const float* n2w   = (const float*)d_in[8];
  const float* n2b   = (const float*)d_in[9];
  const float* w1    = (const float*)d_in[10];
  const float* b1    = (const float*)d_in[11];
  const float* w2    = (const float*)d_in[12];
  const float* b2    = (const float*)d_in[13];
  float* out = (float*)d_out;

  char* ws = (char*)d_ws;
  size_t off = 0;
  auto alloc = [&](size_t bytes) { char* p = ws + off; off += (bytes + 255) & ~(size_t)255; return p; };
  bf16* w_qkv_t  = (bf16*)alloc(576 * 192 * 2);
  bf16* w_proj_t = (bf16*)alloc(192 * 192 * 2);
  bf16* w_mlp1_t = (bf16*)alloc(768 * 192 * 2);
  bf16* w_mlp2_t = (bf16*)alloc(192 * 768 * 2);
  float* bias_tab = (float*)alloc(6 * 64 * 64 * 4);
  bf16* xn    = (bf16*)alloc((size_t)131072 * 192 * 2);
  bf16* qbuf  = (bf16*)alloc((size_t)131072 * 192 * 2);
  bf16* kbuf  = (bf16*)alloc((size_t)131072 * 192 * 2);
  bf16* vtbuf = (bf16*)alloc((size_t)2048 * 6 * 64 * 32 * 2);
  bf16* obuf  = (bf16*)alloc((size_t)131072 * 192 * 2);
  bf16* x2    = (bf16*)alloc((size_t)131072 * 192 * 2);
  bf16* h1  = xn;    // alias: xn/q/k/vt dead after k3 (201 MB)
  bf16* xln = obuf;  // alias: obuf dead after k3 (50 MB)

  k_prep<<<1824, 256, 0, stream>>>(qkv_w, proj_w, w1, w2, rel_b,
                                   w_qkv_t, w_proj_t, w_mlp1_t, w_mlp2_t, bias_tab);
  k1a_ln<<<2048, 512, 0, stream>>>(x, n1w, n1b, xn);
  k1b_qkv<<<dim3(1024, 3), 512, 0, stream>>>(xn, w_qkv_t, qkv_b, qbuf, kbuf, vtbuf);
  k2_attn<<<2048, 384, 0, stream>>>(qbuf, kbuf, vtbuf, bias_tab, obuf);
  k3_proj<<<1024, 512, 0, stream>>>(obuf, w_proj_t, proj_b, x, x2);
  k4ln<<<2048, 512, 0, stream>>>(x2, n2w, n2b, xln);
  k4a_gemm<<<dim3(1024, 4), 512, 0, stream>>>(xln, w_mlp1_t, b1, h1);
  k4b_mlp2<<<1024, 256, 0, stream>>>(h1, w_mlp2_t, b2, x2, out);
}